// Round 1
// baseline (169.256 us; speedup 1.0000x reference)
//
#include <hip/hip_runtime.h>
#include <math.h>

#define NQ 10
#define QDEPTH 6

// State layout: amplitude index i (10 bits) = lane(6 bits)*16 + reg(4 bits).
// Wire w has index-bit significance 2^(9-w):
//   wires 0..5  -> lane bits 5..0  (cross-lane gates, __shfl_xor)
//   wires 6..9  -> reg  bits 3..0  (in-register gates)

__device__ __forceinline__ float shx(float v, int m) { return __shfl_xor(v, m, 64); }

template<int J>  // lane-bit RY, J = 5 - wire
__device__ __forceinline__ void ry_lane(float (&x)[16], int lane, float c, float s) {
  float sg = ((lane >> J) & 1) ? s : -s;   // bit0: c*x - s*p ; bit1: c*x + s*p
#pragma unroll
  for (int r = 0; r < 16; ++r) {
    float p = shx(x[r], 1 << J);
    x[r] = c * x[r] + sg * p;
  }
}

template<int JM> // reg-bit RY, JM = reg bitmask
__device__ __forceinline__ void ry_reg(float (&x)[16], float c, float s) {
#pragma unroll
  for (int r = 0; r < 16; ++r)
    if (!(r & JM)) {
      float x0 = x[r], x1 = x[r | JM];
      x[r]      = c * x0 - s * x1;
      x[r | JM] = s * x0 + c * x1;
    }
}

template<int JC, int JT> // CNOT, ctrl lane bit JC, target lane bit JT
__device__ __forceinline__ void cnot_ll(float (&x)[16], int lane) {
  bool cb = (lane >> JC) & 1;
#pragma unroll
  for (int r = 0; r < 16; ++r) {
    float p = shx(x[r], 1 << JT);
    x[r] = cb ? p : x[r];
  }
}

template<int MC, int MT> // CNOT, ctrl reg mask, target reg mask: static renaming
__device__ __forceinline__ void cnot_rr(float (&x)[16]) {
#pragma unroll
  for (int r = 0; r < 16; ++r)
    if ((r & MC) && !(r & MT)) {
      float t = x[r]; x[r] = x[r | MT]; x[r | MT] = t;
    }
}

// CNOT(5,6): ctrl = lane bit 0, target = reg bit 3
__device__ __forceinline__ void cnot_lr(float (&x)[16], int lane) {
  bool cb = lane & 1;
#pragma unroll
  for (int r = 0; r < 8; ++r) {
    float x0 = x[r], x1 = x[r + 8];
    x[r]     = cb ? x1 : x0;
    x[r + 8] = cb ? x0 : x1;
  }
}

__global__ void qnet_kernel(const float* __restrict__ inp,   // B x 512
                            const float* __restrict__ Wred,  // 10 x 512
                            const float* __restrict__ bred,  // 10
                            const float* __restrict__ qp,    // 15 x 10
                            const float* __restrict__ Wpost, // 2 x 10
                            const float* __restrict__ bpost, // 2
                            float* __restrict__ out,         // B x 2
                            int B) {
  int tid  = blockIdx.x * blockDim.x + threadIdx.x;
  int wave = tid >> 6;
  int lane = tid & 63;
  if (wave >= B) return;

  // ---- fused pre-GEMM: pre[q] = dot(inp[row], Wred[q]) ----
  const float* rowp = inp + (size_t)wave * 512;
  float a[8];
#pragma unroll
  for (int k = 0; k < 8; ++k) a[k] = rowp[lane + 64 * k];
  float th[10];
#pragma unroll
  for (int q = 0; q < 10; ++q) {
    const float* wr = Wred + q * 512;
    float t = 0.f;
#pragma unroll
    for (int k = 0; k < 8; ++k) t += a[k] * wr[lane + 64 * k];
    th[q] = t;
  }
#pragma unroll
  for (int m = 32; m >= 1; m >>= 1)
#pragma unroll
    for (int q = 0; q < 10; ++q) th[q] += shx(th[q], m);

  // ---- init product state: H then RY(q_in) on each wire ----
  // per-qubit amplitude factor: (c - s)/sqrt2 if bit==0 else (c + s)/sqrt2
  float g0[10], g1[10];
#pragma unroll
  for (int q = 0; q < 10; ++q) {
    float t = tanhf(th[q] + bred[q]) * 0.78539816339744831f; // theta/2 = tanh*pi/4
    float c = __cosf(t), s = __sinf(t);
    g0[q] = (c - s) * 0.70710678118654752f;
    g1[q] = (c + s) * 0.70710678118654752f;
  }
  float lf = 1.f;
#pragma unroll
  for (int w = 0; w < 6; ++w) {
    int bit = (lane >> (5 - w)) & 1;
    lf *= bit ? g1[w] : g0[w];
  }
  float x[16];
#pragma unroll
  for (int r = 0; r < 16; ++r) {
    float rf = lf;
#pragma unroll
    for (int w = 6; w < 10; ++w) {
      int bit = (r >> (9 - w)) & 1;
      rf *= bit ? g1[w] : g0[w];
    }
    x[r] = rf;
  }

  // ---- 6 entangling layers ----
  for (int k = 0; k < QDEPTH; ++k) {
    // even CNOTs: (0,1)(2,3)(4,5)(6,7)(8,9)
    cnot_ll<5, 4>(x, lane);
    cnot_ll<3, 2>(x, lane);
    cnot_ll<1, 0>(x, lane);
    cnot_rr<8, 4>(x);
    cnot_rr<2, 1>(x);
    // odd CNOTs: (1,2)(3,4)(5,6)(7,8)
    cnot_ll<4, 3>(x, lane);
    cnot_ll<2, 1>(x, lane);
    cnot_lr(x, lane);
    cnot_rr<4, 2>(x);
    // RY layer, angles q_params[(k+1)*10 + w]
    const float* qr = qp + (k + 1) * 10;
    float t;
    t = qr[0] * 0.5f; ry_lane<5>(x, lane, __cosf(t), __sinf(t));
    t = qr[1] * 0.5f; ry_lane<4>(x, lane, __cosf(t), __sinf(t));
    t = qr[2] * 0.5f; ry_lane<3>(x, lane, __cosf(t), __sinf(t));
    t = qr[3] * 0.5f; ry_lane<2>(x, lane, __cosf(t), __sinf(t));
    t = qr[4] * 0.5f; ry_lane<1>(x, lane, __cosf(t), __sinf(t));
    t = qr[5] * 0.5f; ry_lane<0>(x, lane, __cosf(t), __sinf(t));
    t = qr[6] * 0.5f; ry_reg<8>(x, __cosf(t), __sinf(t));
    t = qr[7] * 0.5f; ry_reg<4>(x, __cosf(t), __sinf(t));
    t = qr[8] * 0.5f; ry_reg<2>(x, __cosf(t), __sinf(t));
    t = qr[9] * 0.5f; ry_reg<1>(x, __cosf(t), __sinf(t));
  }

  // ---- expval Z per wire ----
  float z[10];
  float S = 0.f, z6 = 0.f, z7 = 0.f, z8 = 0.f, z9 = 0.f;
#pragma unroll
  for (int r = 0; r < 16; ++r) {
    float q2 = x[r] * x[r];
    S  += q2;
    z6 += (r & 8) ? -q2 : q2;
    z7 += (r & 4) ? -q2 : q2;
    z8 += (r & 2) ? -q2 : q2;
    z9 += (r & 1) ? -q2 : q2;
  }
  z[6] = z6; z[7] = z7; z[8] = z8; z[9] = z9;
#pragma unroll
  for (int w = 0; w < 6; ++w) z[w] = ((lane >> (5 - w)) & 1) ? -S : S;
#pragma unroll
  for (int m = 32; m >= 1; m >>= 1)
#pragma unroll
    for (int w = 0; w < 10; ++w) z[w] += shx(z[w], m);

  // ---- post-projection ----
  if (lane == 0) {
    float o0 = bpost[0], o1 = bpost[1];
#pragma unroll
    for (int w = 0; w < 10; ++w) {
      o0 += z[w] * Wpost[w];
      o1 += z[w] * Wpost[10 + w];
    }
    out[2 * (size_t)wave]     = o0;
    out[2 * (size_t)wave + 1] = o1;
  }
}

extern "C" void kernel_launch(void* const* d_in, const int* in_sizes, int n_in,
                              void* d_out, int out_size, void* d_ws, size_t ws_size,
                              hipStream_t stream) {
  const float* inp   = (const float*)d_in[0];
  const float* Wred  = (const float*)d_in[1];
  const float* bred  = (const float*)d_in[2];
  const float* qp    = (const float*)d_in[3];
  const float* Wpost = (const float*)d_in[4];
  const float* bpost = (const float*)d_in[5];
  float* out = (float*)d_out;

  int B = in_sizes[0] / 512;
  int threads = 256;
  int blocks = (B * 64 + threads - 1) / threads;
  qnet_kernel<<<blocks, threads, 0, stream>>>(inp, Wred, bred, qp, Wpost, bpost, out, B);
}

// Round 2
// 113.268 us; speedup vs baseline: 1.4943x; 1.4943x over previous
//
#include <hip/hip_runtime.h>
#include <math.h>

#define QDEPTH 6

// State layout: amplitude index (10 bits) = lane(6)*16 + reg(4).
// wire w in 0..5  -> lane bit (5-w);  wire w in 6..9 -> reg bit (9-w).

__device__ __forceinline__ float shx(float v, int m) { return __shfl_xor(v, m, 64); }

template<int CTRL>
__device__ __forceinline__ float dpp_mov(float v) {
  int i = __float_as_int(v);
  int r = __builtin_amdgcn_update_dpp(i, i, CTRL, 0xF, 0xF, true);
  return __int_as_float(r);
}

template<int CTRL>
__device__ __forceinline__ float dpp_add0(float v) {
  int i = __float_as_int(v);
  int r = __builtin_amdgcn_update_dpp(0, i, CTRL, 0xF, 0xF, false);
  return v + __int_as_float(r);
}

// full-wave sum; result valid in lane 63
__device__ __forceinline__ float wave_sum(float v) {
  v = dpp_add0<0x111>(v);  // row_shr:1
  v = dpp_add0<0x112>(v);  // row_shr:2
  v = dpp_add0<0x114>(v);  // row_shr:4
  v = dpp_add0<0x118>(v);  // row_shr:8
  v = dpp_add0<0x142>(v);  // row_bcast:15
  v = dpp_add0<0x143>(v);  // row_bcast:31
  return v;
}

__device__ __forceinline__ float bcast63(float v) {
  return __int_as_float(__builtin_amdgcn_readlane(__float_as_int(v), 63));
}

__device__ __forceinline__ void pl32_swap(float& a, float& b) {
  asm("v_permlane32_swap_b32 %0, %1" : "+v"(a), "+v"(b));
}
__device__ __forceinline__ void pl16_swap(float& a, float& b) {
  asm("v_permlane16_swap_b32 %0, %1" : "+v"(a), "+v"(b));
}

// RY on lane bit 5 (IS32) or bit 4 (!IS32) via permlane pair-trick (VALU pipe).
template<bool IS32>
__device__ __forceinline__ void ry_pl(float (&x)[16], float c, float s) {
#pragma unroll
  for (int r = 0; r < 16; r += 2) {
    float a = x[r], b = x[r + 1];
    if (IS32) pl32_swap(a, b); else pl16_swap(a, b);
    // now (a,b) = (bit=0 amp, bit=1 amp) in every lane
    float n0 = c * a - s * b;
    float n1 = s * a + c * b;
    if (IS32) pl32_swap(n0, n1); else pl16_swap(n0, n1);
    x[r] = n0; x[r + 1] = n1;
  }
}

// RY on lane bits 1/0 via DPP quad_perm. sg = (lane bit) ? +s : -s
template<int CTRL>
__device__ __forceinline__ void ry_dpp(float (&x)[16], float c, float sg) {
#pragma unroll
  for (int r = 0; r < 16; ++r) {
    float p = dpp_mov<CTRL>(x[r]);
    x[r] = c * x[r] + sg * p;
  }
}

// RY on lane bits 3/2 via bpermute
template<int M>
__device__ __forceinline__ void ry_sh(float (&x)[16], float c, float sg) {
#pragma unroll
  for (int r = 0; r < 16; ++r) {
    float p = shx(x[r], M);
    x[r] = c * x[r] + sg * p;
  }
}

template<int JM> // RY on reg bit
__device__ __forceinline__ void ry_reg(float (&x)[16], float c, float s) {
#pragma unroll
  for (int r = 0; r < 16; ++r)
    if (!(r & JM)) {
      float x0 = x[r], x1 = x[r | JM];
      x[r]      = c * x0 - s * x1;
      x[r | JM] = s * x0 + c * x1;
    }
}

template<int MC, int MT> // CNOT on reg bits: static renaming (free)
__device__ __forceinline__ void cnot_rr(float (&x)[16]) {
#pragma unroll
  for (int r = 0; r < 16; ++r)
    if ((r & MC) && !(r & MT)) {
      float t = x[r]; x[r] = x[r | MT]; x[r | MT] = t;
    }
}

// CNOT(5,6): ctrl = lane bit 0, target = reg bit 3
__device__ __forceinline__ void cnot_lr56(float (&x)[16], int lane) {
  bool cb = lane & 1;
#pragma unroll
  for (int r = 0; r < 8; ++r) {
    float lo = x[r], hi = x[r + 8];
    x[r]     = cb ? hi : lo;
    x[r + 8] = cb ? lo : hi;
  }
}

__global__ void __launch_bounds__(256) qnet_kernel(
    const float* __restrict__ inp,   // B x 512
    const float* __restrict__ Wred,  // 10 x 512
    const float* __restrict__ bred,  // 10
    const float* __restrict__ qp,    // 15 x 10
    const float* __restrict__ Wpost, // 2 x 10
    const float* __restrict__ bpost, // 2
    float* __restrict__ out,         // B x 2
    int B) {
  int tid  = blockIdx.x * 256 + threadIdx.x;
  int wv   = tid >> 6;
  int lane = tid & 63;
  if (wv >= B) return;

  // composed lane permutation for the 5 lane-CNOTs of one layer:
  // even (0,1)(2,3)(4,5) then odd (1,2)(3,4); src = E(O(lane))
  int o = lane ^ (((lane >> 4) & 1) << 3) ^ (((lane >> 2) & 1) << 1);
  int psrc = o ^ (((o >> 5) & 1) << 4) ^ (((o >> 3) & 1) << 2) ^ ((o >> 1) & 1);

  // ---- fused pre-GEMM (float4) ----
  const float4* row4 = (const float4*)(inp + (size_t)wv * 512);
  float4 a0 = row4[lane], a1 = row4[lane + 64];
  float th[10];
#pragma unroll
  for (int q = 0; q < 10; ++q) {
    const float4* w4 = (const float4*)(Wred + q * 512);
    float4 b0 = w4[lane], b1 = w4[lane + 64];
    float t = a0.x * b0.x + a0.y * b0.y + a0.z * b0.z + a0.w * b0.w;
    t += a1.x * b1.x + a1.y * b1.y + a1.z * b1.z + a1.w * b1.w;
    th[q] = t;
  }

  // ---- per-qubit product-state factors: H then RY(q_in) ----
  float g0[10], g1[10];
#pragma unroll
  for (int q = 0; q < 10; ++q) {
    float tot = bcast63(wave_sum(th[q])) + bred[q];
    float xc = fminf(fmaxf(tot, -15.f), 15.f);
    float u = __expf(2.f * xc);
    float tanhv = (u - 1.f) * __builtin_amdgcn_rcpf(u + 1.f);
    float t = tanhv * 0.78539816339744831f;  // theta/2 = tanh * pi/4
    float c = __cosf(t), s = __sinf(t);
    g0[q] = (c - s) * 0.70710678118654752f;
    g1[q] = (c + s) * 0.70710678118654752f;
  }
  float lf = 1.f;
#pragma unroll
  for (int w = 0; w < 6; ++w)
    lf *= ((lane >> (5 - w)) & 1) ? g1[w] : g0[w];
  float f67[4], f89[4];
#pragma unroll
  for (int i = 0; i < 4; ++i) {
    f67[i] = ((i & 2) ? g1[6] : g0[6]) * ((i & 1) ? g1[7] : g0[7]);
    f89[i] = ((i & 2) ? g1[8] : g0[8]) * ((i & 1) ? g1[9] : g0[9]);
  }
  float x[16];
#pragma unroll
  for (int r = 0; r < 16; ++r) x[r] = lf * f67[r >> 2] * f89[r & 3];

  // ---- entangling layers ----
#pragma unroll
  for (int k = 0; k < QDEPTH; ++k) {
    const float* qr = qp + (k + 1) * 10;
    // 5 lane CNOTs composed into one bpermute per register
#pragma unroll
    for (int r = 0; r < 16; ++r) x[r] = __shfl(x[r], psrc, 64);
    cnot_rr<8, 4>(x);   // (6,7)
    cnot_rr<2, 1>(x);   // (8,9)
    cnot_lr56(x, lane); // (5,6)
    cnot_rr<4, 2>(x);   // (7,8)

    float t, c, s, sg;
    t = qr[0] * 0.5f; c = __cosf(t); s = __sinf(t); ry_pl<true>(x, c, s);   // wire0, mask32
    t = qr[1] * 0.5f; c = __cosf(t); s = __sinf(t); ry_pl<false>(x, c, s);  // wire1, mask16
    t = qr[2] * 0.5f; c = __cosf(t); s = __sinf(t);
    sg = (lane & 8) ? s : -s; ry_sh<8>(x, c, sg);                            // wire2
    t = qr[3] * 0.5f; c = __cosf(t); s = __sinf(t);
    sg = (lane & 4) ? s : -s; ry_sh<4>(x, c, sg);                            // wire3
    t = qr[4] * 0.5f; c = __cosf(t); s = __sinf(t);
    sg = (lane & 2) ? s : -s; ry_dpp<0x4E>(x, c, sg);                        // wire4, xor2
    t = qr[5] * 0.5f; c = __cosf(t); s = __sinf(t);
    sg = (lane & 1) ? s : -s; ry_dpp<0xB1>(x, c, sg);                        // wire5, xor1
    t = qr[6] * 0.5f; c = __cosf(t); s = __sinf(t); ry_reg<8>(x, c, s);
    t = qr[7] * 0.5f; c = __cosf(t); s = __sinf(t); ry_reg<4>(x, c, s);
    t = qr[8] * 0.5f; c = __cosf(t); s = __sinf(t); ry_reg<2>(x, c, s);
    t = qr[9] * 0.5f; c = __cosf(t); s = __sinf(t); ry_reg<1>(x, c, s);
  }

  // ---- expval Z projected onto W_post, then 2 wave reductions ----
  float S = 0.f, z6 = 0.f, z7 = 0.f, z8 = 0.f, z9 = 0.f;
#pragma unroll
  for (int r = 0; r < 16; ++r) {
    float q2 = x[r] * x[r];
    S  += q2;
    z6 += (r & 8) ? -q2 : q2;
    z7 += (r & 4) ? -q2 : q2;
    z8 += (r & 2) ? -q2 : q2;
    z9 += (r & 1) ? -q2 : q2;
  }
  float A0 = 0.f, A1 = 0.f;
#pragma unroll
  for (int w = 0; w < 6; ++w) {
    bool b = (lane >> (5 - w)) & 1;
    A0 += b ? -Wpost[w] : Wpost[w];
    A1 += b ? -Wpost[10 + w] : Wpost[10 + w];
  }
  float o0 = A0 * S + Wpost[6] * z6 + Wpost[7] * z7 + Wpost[8] * z8 + Wpost[9] * z9;
  float o1 = A1 * S + Wpost[16] * z6 + Wpost[17] * z7 + Wpost[18] * z8 + Wpost[19] * z9;
  o0 = wave_sum(o0);
  o1 = wave_sum(o1);
  if (lane == 63) {
    out[2 * (size_t)wv]     = o0 + bpost[0];
    out[2 * (size_t)wv + 1] = o1 + bpost[1];
  }
}

extern "C" void kernel_launch(void* const* d_in, const int* in_sizes, int n_in,
                              void* d_out, int out_size, void* d_ws, size_t ws_size,
                              hipStream_t stream) {
  const float* inp   = (const float*)d_in[0];
  const float* Wred  = (const float*)d_in[1];
  const float* bred  = (const float*)d_in[2];
  const float* qp    = (const float*)d_in[3];
  const float* Wpost = (const float*)d_in[4];
  const float* bpost = (const float*)d_in[5];
  float* out = (float*)d_out;

  int B = in_sizes[0] / 512;
  int threads = 256;
  int blocks = (B * 64 + threads - 1) / threads;
  qnet_kernel<<<blocks, threads, 0, stream>>>(inp, Wred, bred, qp, Wpost, bpost, out, B);
}

// Round 3
// 109.808 us; speedup vs baseline: 1.5414x; 1.0315x over previous
//
#include <hip/hip_runtime.h>
#include <math.h>

#define QDEPTH 6

typedef float f2 __attribute__((ext_vector_type(2)));

// State layout: amplitude index (10 bits) = lane(6) << 4 | reg(4).
// reg(4) = arr(3 bits: A2 A1 A0 = amp bits 3,2,1) + comp(1 bit = amp bit 0).
// wires 0..5 -> lane bits 5..0 ; wires 6,7,8 -> arr bits A2,A1,A0 ; wire 9 -> comp.

__device__ __forceinline__ float shx(float v, int m) { return __shfl_xor(v, m, 64); }

template<int CTRL>
__device__ __forceinline__ float dpp_mov(float v) {
  int i = __float_as_int(v);
  int r = __builtin_amdgcn_update_dpp(i, i, CTRL, 0xF, 0xF, true);
  return __int_as_float(r);
}

template<int CTRL>
__device__ __forceinline__ float dpp_add0(float v) {
  int i = __float_as_int(v);
  int r = __builtin_amdgcn_update_dpp(0, i, CTRL, 0xF, 0xF, false);
  return v + __int_as_float(r);
}

// full-wave sum; result valid in lane 63
__device__ __forceinline__ float wave_sum(float v) {
  v = dpp_add0<0x111>(v);  // row_shr:1
  v = dpp_add0<0x112>(v);  // row_shr:2
  v = dpp_add0<0x114>(v);  // row_shr:4
  v = dpp_add0<0x118>(v);  // row_shr:8
  v = dpp_add0<0x142>(v);  // row_bcast:15
  v = dpp_add0<0x143>(v);  // row_bcast:31
  return v;
}

__device__ __forceinline__ float bcast63(float v) {
  return __int_as_float(__builtin_amdgcn_readlane(__float_as_int(v), 63));
}

__device__ __forceinline__ void pl32_swap(float& a, float& b) {
  asm("v_permlane32_swap_b32 %0, %1" : "+v"(a), "+v"(b));
}
__device__ __forceinline__ void pl16_swap(float& a, float& b) {
  asm("v_permlane16_swap_b32 %0, %1" : "+v"(a), "+v"(b));
}

__device__ __forceinline__ f2 pk_mul(f2 a, f2 b) {
  f2 d; asm("v_pk_mul_f32 %0, %1, %2" : "=v"(d) : "v"(a), "v"(b)); return d;
}
__device__ __forceinline__ f2 pk_fma(f2 a, f2 b, f2 c) {
  f2 d; asm("v_pk_fma_f32 %0, %1, %2, %3" : "=v"(d) : "v"(a), "v"(b), "v"(c)); return d;
}

__global__ void __launch_bounds__(256) qnet_kernel(
    const float* __restrict__ inp,   // B x 512
    const float* __restrict__ Wred,  // 10 x 512
    const float* __restrict__ bred,  // 10
    const float* __restrict__ qp,    // 15 x 10
    const float* __restrict__ Wpost, // 2 x 10
    const float* __restrict__ bpost, // 2
    float* __restrict__ out,         // B x 2
    int B) {
  int tid  = blockIdx.x * 256 + threadIdx.x;
  int wv   = tid >> 6;
  int lane = tid & 63;
  if (wv >= B) return;

  // composed lane permutation of the layer's 5 lane-lane CNOTs (even then odd)
  int o = lane ^ (((lane >> 4) & 1) << 3) ^ (((lane >> 2) & 1) << 1);
  int psrc = o ^ (((o >> 5) & 1) << 4) ^ (((o >> 3) & 1) << 2) ^ ((o >> 1) & 1);

  // ---- fused pre-GEMM (float4) ----
  const float4* row4 = (const float4*)(inp + (size_t)wv * 512);
  float4 a0 = row4[lane], a1 = row4[lane + 64];
  float th[10];
#pragma unroll
  for (int q = 0; q < 10; ++q) {
    const float4* w4 = (const float4*)(Wred + q * 512);
    float4 b0 = w4[lane], b1 = w4[lane + 64];
    float t = a0.x * b0.x + a0.y * b0.y + a0.z * b0.z + a0.w * b0.w;
    t += a1.x * b1.x + a1.y * b1.y + a1.z * b1.z + a1.w * b1.w;
    th[q] = t;
  }

  // ---- per-qubit product-state factors: H then RY(q_in) ----
  float g0[10], g1[10];
#pragma unroll
  for (int q = 0; q < 10; ++q) {
    float tot = bcast63(wave_sum(th[q])) + bred[q];
    float xc = fminf(fmaxf(tot, -15.f), 15.f);
    float u = __expf(2.f * xc);
    float tanhv = (u - 1.f) * __builtin_amdgcn_rcpf(u + 1.f);
    float t = tanhv * 0.78539816339744831f;  // theta/2 = tanh * pi/4
    float c = __cosf(t), s = __sinf(t);
    g0[q] = (c - s) * 0.70710678118654752f;
    g1[q] = (c + s) * 0.70710678118654752f;
  }
  float lf = 1.f;
#pragma unroll
  for (int w = 0; w < 6; ++w)
    lf *= ((lane >> (5 - w)) & 1) ? g1[w] : g0[w];
  float f67v[4];
#pragma unroll
  for (int j = 0; j < 4; ++j)
    f67v[j] = ((j & 2) ? g1[6] : g0[6]) * ((j & 1) ? g1[7] : g0[7]);
  f2 F89v[2];
  F89v[0] = (f2){ g0[8] * g0[9], g0[8] * g1[9] };
  F89v[1] = (f2){ g1[8] * g0[9], g1[8] * g1[9] };
  f2 x2[8];
#pragma unroll
  for (int i = 0; i < 8; ++i) {
    float m = lf * f67v[i >> 1];
    x2[i] = (f2){ m * F89v[i & 1].x, m * F89v[i & 1].y };
  }

  bool cb = lane & 1;

  // ---- entangling layers ----
#pragma unroll
  for (int k = 0; k < QDEPTH; ++k) {
    const float* qr = qp + (k + 1) * 10;

    // composed lane-lane CNOTs: one bpermute per 32-bit half
#pragma unroll
    for (int i = 0; i < 8; ++i) {
      float lo = __shfl(x2[i].x, psrc, 64);
      float hi = __shfl(x2[i].y, psrc, 64);
      x2[i] = (f2){lo, hi};
    }
    // CNOT(6,7): rename A2=1: swap A1 -> (4,6),(5,7)
    { f2 t = x2[4]; x2[4] = x2[6]; x2[6] = t;
      t = x2[5]; x2[5] = x2[7]; x2[7] = t; }
    // CNOT(8,9): comp-swap on A0=1 entries -> DEFERRED into RY9 (flags below)
    // CNOT(7,8): rename A1=1: swap A0 -> (2,3),(6,7); flags become {A0^A1=1} = {1,2,5,6}
    { f2 t = x2[2]; x2[2] = x2[3]; x2[3] = t;
      t = x2[6]; x2[6] = x2[7]; x2[7] = t; }

    // RY wire9 (comp bit), absorbing the deferred comp-swap on entries {1,2,5,6}
    { float t9 = qr[9] * 0.5f; float c = __cosf(t9), s = __sinf(t9);
#pragma unroll
      for (int i = 0; i < 8; ++i) {
        bool flg = (i == 1 || i == 2 || i == 5 || i == 6);
        float lo = x2[i].x, hi = x2[i].y;
        float nlo, nhi;
        if (flg) { nlo = c * hi - s * lo; nhi = s * hi + c * lo; }  // R ∘ SWAP
        else     { nlo = c * lo - s * hi; nhi = s * lo + c * hi; }
        x2[i] = (f2){nlo, nhi};
      } }

    // RY wire6 (A2), absorbing CNOT(5,6) (lane-bit0-conditioned A2 swap)
    { float t6 = qr[6] * 0.5f; float c = __cosf(t6), s = __sinf(t6);
      float Ac = cb ? -s : c;  float Bc = cb ? c : -s;
      float Cc = cb ? c : s;   float Dc = cb ? s : c;
      f2 AA = {Ac, Ac}, BB = {Bc, Bc}, CC = {Cc, Cc}, DD = {Dc, Dc};
#pragma unroll
      for (int i = 0; i < 4; ++i) {
        f2 u = x2[i], w = x2[i + 4];
        x2[i]     = pk_fma(u, AA, pk_mul(w, BB));
        x2[i + 4] = pk_fma(u, CC, pk_mul(w, DD));
      } }

    // RY wire7 (A1)
    { float t7 = qr[7] * 0.5f; float c = __cosf(t7), s = __sinf(t7);
      f2 cc = {c, c}, ss = {s, s}, ns = {-s, -s};
#pragma unroll
      for (int i = 0; i < 8; ++i) if (!(i & 2)) {
        f2 u = x2[i], w = x2[i | 2];
        x2[i]     = pk_fma(u, cc, pk_mul(w, ns));
        x2[i | 2] = pk_fma(w, cc, pk_mul(u, ss));
      } }

    // RY wire8 (A0)
    { float t8 = qr[8] * 0.5f; float c = __cosf(t8), s = __sinf(t8);
      f2 cc = {c, c}, ss = {s, s}, ns = {-s, -s};
#pragma unroll
      for (int i = 0; i < 8; ++i) if (!(i & 1)) {
        f2 u = x2[i], w = x2[i | 1];
        x2[i]     = pk_fma(u, cc, pk_mul(w, ns));
        x2[i | 1] = pk_fma(w, cc, pk_mul(u, ss));
      } }

    // RY wire0 (lane bit5): permlane32 pair-trick, packed rotation
    { float t0 = qr[0] * 0.5f; float c = __cosf(t0), s = __sinf(t0);
      f2 cc = {c, c}, ss = {s, s}, ns = {-s, -s};
#pragma unroll
      for (int j = 0; j < 4; ++j) {
        float ax = x2[2 * j].x,     ay = x2[2 * j].y;
        float bx = x2[2 * j + 1].x, by = x2[2 * j + 1].y;
        pl32_swap(ax, bx); pl32_swap(ay, by);
        f2 u = {ax, ay}, v = {bx, by};
        f2 nu = pk_fma(u, cc, pk_mul(v, ns));
        f2 nv = pk_fma(v, cc, pk_mul(u, ss));
        float nux = nu.x, nuy = nu.y, nvx = nv.x, nvy = nv.y;
        pl32_swap(nux, nvx); pl32_swap(nuy, nvy);
        x2[2 * j] = (f2){nux, nuy}; x2[2 * j + 1] = (f2){nvx, nvy};
      } }

    // RY wire1 (lane bit4): permlane16 pair-trick
    { float t1 = qr[1] * 0.5f; float c = __cosf(t1), s = __sinf(t1);
      f2 cc = {c, c}, ss = {s, s}, ns = {-s, -s};
#pragma unroll
      for (int j = 0; j < 4; ++j) {
        float ax = x2[2 * j].x,     ay = x2[2 * j].y;
        float bx = x2[2 * j + 1].x, by = x2[2 * j + 1].y;
        pl16_swap(ax, bx); pl16_swap(ay, by);
        f2 u = {ax, ay}, v = {bx, by};
        f2 nu = pk_fma(u, cc, pk_mul(v, ns));
        f2 nv = pk_fma(v, cc, pk_mul(u, ss));
        float nux = nu.x, nuy = nu.y, nvx = nv.x, nvy = nv.y;
        pl16_swap(nux, nvx); pl16_swap(nuy, nvy);
        x2[2 * j] = (f2){nux, nuy}; x2[2 * j + 1] = (f2){nvx, nvy};
      } }

    // RY wire2 (lane bit3): shfl_xor 8 (DS pipe), packed FMA
    { float t2 = qr[2] * 0.5f; float c = __cosf(t2), s = __sinf(t2);
      float sg = (lane & 8) ? s : -s;
      f2 cc = {c, c}, gg = {sg, sg};
#pragma unroll
      for (int i = 0; i < 8; ++i) {
        f2 p = { shx(x2[i].x, 8), shx(x2[i].y, 8) };
        x2[i] = pk_fma(x2[i], cc, pk_mul(p, gg));
      } }

    // RY wire3 (lane bit2): shfl_xor 4 (DS pipe), packed FMA
    { float t3 = qr[3] * 0.5f; float c = __cosf(t3), s = __sinf(t3);
      float sg = (lane & 4) ? s : -s;
      f2 cc = {c, c}, gg = {sg, sg};
#pragma unroll
      for (int i = 0; i < 8; ++i) {
        f2 p = { shx(x2[i].x, 4), shx(x2[i].y, 4) };
        x2[i] = pk_fma(x2[i], cc, pk_mul(p, gg));
      } }

    // RY wire4 (lane bit1): DPP quad_perm xor2
    { float t4 = qr[4] * 0.5f; float c = __cosf(t4), s = __sinf(t4);
      float sg = (lane & 2) ? s : -s;
      f2 cc = {c, c}, gg = {sg, sg};
#pragma unroll
      for (int i = 0; i < 8; ++i) {
        f2 p = { dpp_mov<0x4E>(x2[i].x), dpp_mov<0x4E>(x2[i].y) };
        x2[i] = pk_fma(x2[i], cc, pk_mul(p, gg));
      } }

    // RY wire5 (lane bit0): DPP quad_perm xor1
    { float t5 = qr[5] * 0.5f; float c = __cosf(t5), s = __sinf(t5);
      float sg = (lane & 1) ? s : -s;
      f2 cc = {c, c}, gg = {sg, sg};
#pragma unroll
      for (int i = 0; i < 8; ++i) {
        f2 p = { dpp_mov<0xB1>(x2[i].x), dpp_mov<0xB1>(x2[i].y) };
        x2[i] = pk_fma(x2[i], cc, pk_mul(p, gg));
      } }
  }

  // ---- expval Z (packed partial sums) ----
  f2 one = {1.f, 1.f}, mone = {-1.f, -1.f};
  f2 P = {0.f, 0.f}, P6 = {0.f, 0.f}, P7 = {0.f, 0.f}, P8 = {0.f, 0.f};
#pragma unroll
  for (int i = 0; i < 8; ++i) {
    f2 sq = pk_mul(x2[i], x2[i]);
    P  = pk_fma(sq, one, P);
    P6 = pk_fma(sq, (i & 4) ? mone : one, P6);
    P7 = pk_fma(sq, (i & 2) ? mone : one, P7);
    P8 = pk_fma(sq, (i & 1) ? mone : one, P8);
  }
  float S  = P.x + P.y;
  float z9 = P.x - P.y;
  float z6 = P6.x + P6.y, z7 = P7.x + P7.y, z8 = P8.x + P8.y;

  // wires 0..5: z_w = ±S by lane bit; project onto W_post before reducing
  float A0 = 0.f, A1 = 0.f;
#pragma unroll
  for (int w = 0; w < 6; ++w) {
    bool b = (lane >> (5 - w)) & 1;
    A0 += b ? -Wpost[w] : Wpost[w];
    A1 += b ? -Wpost[10 + w] : Wpost[10 + w];
  }
  float o0 = A0 * S + Wpost[6] * z6 + Wpost[7] * z7 + Wpost[8] * z8 + Wpost[9] * z9;
  float o1 = A1 * S + Wpost[16] * z6 + Wpost[17] * z7 + Wpost[18] * z8 + Wpost[19] * z9;
  o0 = wave_sum(o0);
  o1 = wave_sum(o1);
  if (lane == 63) {
    out[2 * (size_t)wv]     = o0 + bpost[0];
    out[2 * (size_t)wv + 1] = o1 + bpost[1];
  }
}

extern "C" void kernel_launch(void* const* d_in, const int* in_sizes, int n_in,
                              void* d_out, int out_size, void* d_ws, size_t ws_size,
                              hipStream_t stream) {
  const float* inp   = (const float*)d_in[0];
  const float* Wred  = (const float*)d_in[1];
  const float* bred  = (const float*)d_in[2];
  const float* qp    = (const float*)d_in[3];
  const float* Wpost = (const float*)d_in[4];
  const float* bpost = (const float*)d_in[5];
  float* out = (float*)d_out;

  int B = in_sizes[0] / 512;
  int threads = 256;
  int blocks = (B * 64 + threads - 1) / threads;
  qnet_kernel<<<blocks, threads, 0, stream>>>(inp, Wred, bred, qp, Wpost, bpost, out, B);
}

// Round 5
// 99.248 us; speedup vs baseline: 1.7054x; 1.1064x over previous
//
#include <hip/hip_runtime.h>
#include <math.h>

#define QDEPTH 6

typedef _Float16 h2 __attribute__((ext_vector_type(2)));

__device__ __forceinline__ int   h2i(h2 v)  { return __builtin_bit_cast(int, v); }
__device__ __forceinline__ h2    ih2(int v) { return __builtin_bit_cast(h2, v); }

// swap the two f16 halves of a 32-bit reg (v_alignbit)
__device__ __forceinline__ h2 hswap(h2 v) {
  unsigned u = __builtin_bit_cast(unsigned, v);
  u = (u >> 16) | (u << 16);
  return __builtin_bit_cast(h2, u);
}

__device__ __forceinline__ h2 cvt_pk(float a, float b) {
  return __builtin_bit_cast(h2, __builtin_amdgcn_cvt_pkrtz(a, b));
}

__device__ __forceinline__ h2 bper(int addr, h2 v) {
  return ih2(__builtin_amdgcn_ds_bpermute(addr, h2i(v)));
}

template<int CTRL>
__device__ __forceinline__ h2 dpph(h2 v) {
  int i = h2i(v);
  return ih2(__builtin_amdgcn_update_dpp(i, i, CTRL, 0xF, 0xF, true));
}

template<int CTRL>
__device__ __forceinline__ float dpp_add0(float v) {
  int i = __float_as_int(v);
  int r = __builtin_amdgcn_update_dpp(0, i, CTRL, 0xF, 0xF, false);
  return v + __int_as_float(r);
}

// full-wave sum; result valid in lane 63
__device__ __forceinline__ float wave_sum(float v) {
  v = dpp_add0<0x111>(v);
  v = dpp_add0<0x112>(v);
  v = dpp_add0<0x114>(v);
  v = dpp_add0<0x118>(v);
  v = dpp_add0<0x142>(v);
  v = dpp_add0<0x143>(v);
  return v;
}

__device__ __forceinline__ float bcast63(float v) {
  return __int_as_float(__builtin_amdgcn_readlane(__float_as_int(v), 63));
}

__device__ __forceinline__ void pl32s(int& a, int& b) {
  asm("v_permlane32_swap_b32 %0, %1" : "+v"(a), "+v"(b));
}
__device__ __forceinline__ void pl16s(int& a, int& b) {
  asm("v_permlane16_swap_b32 %0, %1" : "+v"(a), "+v"(b));
}

// ---------------- setup: batch-independent packed f16 gate coefficients ----
// layout: per layer k (stride 32 u32): wire w<9 at w*3: {cc, ss, ns}; wire9 at 27: {cc9, ms9=(-s,+s)}
__global__ void setup_kernel(const float* __restrict__ qp, unsigned* __restrict__ cb) {
  int t = threadIdx.x;
  if (t >= 60) return;
  int k = t / 10, w = t % 10;
  float ang = qp[(k + 1) * 10 + w] * 0.5f;
  float c = __cosf(ang), s = __sinf(ang);
  unsigned* p = cb + k * 32 + ((w < 9) ? w * 3 : 27);
  h2 cc = { (_Float16)c, (_Float16)c };
  if (w < 9) {
    h2 ss = { (_Float16)s,  (_Float16)s };
    h2 ns = { (_Float16)(-s), (_Float16)(-s) };
    p[0] = __builtin_bit_cast(unsigned, cc);
    p[1] = __builtin_bit_cast(unsigned, ss);
    p[2] = __builtin_bit_cast(unsigned, ns);
  } else {
    h2 ms = { (_Float16)(-s), (_Float16)s };
    p[0] = __builtin_bit_cast(unsigned, cc);
    p[1] = __builtin_bit_cast(unsigned, ms);
  }
}

// ---------------- main ----------------
__global__ void __launch_bounds__(256) qnet_kernel(
    const float* __restrict__ inp,   // B x 512
    const float* __restrict__ Wred,  // 10 x 512
    const float* __restrict__ bred,  // 10
    const unsigned* __restrict__ cb, // packed coefficients (from setup)
    const float* __restrict__ Wpost, // 2 x 10
    const float* __restrict__ bpost, // 2
    float* __restrict__ out,         // B x 2
    int B) {
  int tid  = blockIdx.x * 256 + threadIdx.x;
  int wv   = tid >> 6;
  int lane = tid & 63;
  if (wv >= B) return;

  // composed lane permutation of the layer's 5 lane-lane CNOTs (even then odd)
  int o = lane ^ (((lane >> 4) & 1) << 3) ^ (((lane >> 2) & 1) << 1);
  int psrc = o ^ (((o >> 5) & 1) << 4) ^ (((o >> 3) & 1) << 2) ^ ((o >> 1) & 1);
  int addrP  = psrc << 2;
  int addrX8 = (lane ^ 8) << 2;
  int addrX4 = (lane ^ 4) << 2;
  bool cb1 = lane & 1;

  // ---- fused pre-GEMM (float4) ----
  const float4* row4 = (const float4*)(inp + (size_t)wv * 512);
  float4 a0 = row4[lane], a1 = row4[lane + 64];
  float th[10];
#pragma unroll
  for (int q = 0; q < 10; ++q) {
    const float4* w4 = (const float4*)(Wred + q * 512);
    float4 b0 = w4[lane], b1 = w4[lane + 64];
    float t = a0.x * b0.x + a0.y * b0.y + a0.z * b0.z + a0.w * b0.w;
    t += a1.x * b1.x + a1.y * b1.y + a1.z * b1.z + a1.w * b1.w;
    th[q] = t;
  }

  // ---- per-qubit product-state factors: H then RY(q_in) ----
  float g0[10], g1[10];
#pragma unroll
  for (int q = 0; q < 10; ++q) {
    float tot = bcast63(wave_sum(th[q])) + bred[q];
    float xc = fminf(fmaxf(tot, -15.f), 15.f);
    float u = __expf(2.f * xc);
    float tanhv = (u - 1.f) * __builtin_amdgcn_rcpf(u + 1.f);
    float t = tanhv * 0.78539816339744831f;  // theta/2 = tanh * pi/4
    float c = __cosf(t), s = __sinf(t);
    g0[q] = (c - s) * 0.70710678118654752f;
    g1[q] = (c + s) * 0.70710678118654752f;
  }
  float lf = 1.f;
#pragma unroll
  for (int w = 0; w < 6; ++w)
    lf *= ((lane >> (5 - w)) & 1) ? g1[w] : g0[w];
  float f67v[4];
#pragma unroll
  for (int j = 0; j < 4; ++j)
    f67v[j] = ((j & 2) ? g1[6] : g0[6]) * ((j & 1) ? g1[7] : g0[7]);
  float F89x[2], F89y[2];
  F89x[0] = g0[8] * g0[9]; F89y[0] = g0[8] * g1[9];
  F89x[1] = g1[8] * g0[9]; F89y[1] = g1[8] * g1[9];

  // state: 8 packed regs; reg i = (A2 A1 A0) = amp bits from wires 6,7,8;
  // packed halves = wire 9 (comp bit).
  h2 x[8];
#pragma unroll
  for (int i = 0; i < 8; ++i) {
    float m = lf * f67v[i >> 1];
    x[i] = cvt_pk(m * F89x[i & 1], m * F89y[i & 1]);
  }

  // ---- entangling layers ----
  for (int k = 0; k < QDEPTH; ++k) {
    const unsigned* L = cb + k * 32;
    h2 cc9 = ih2(L[27]), ms9 = ih2(L[28]);
    h2 cc6 = ih2(L[18]), ss6 = ih2(L[19]), ns6 = ih2(L[20]);
    h2 cc7 = ih2(L[21]), ss7 = ih2(L[22]), ns7 = ih2(L[23]);
    h2 cc8 = ih2(L[24]), ss8 = ih2(L[25]), ns8 = ih2(L[26]);
    h2 cc0 = ih2(L[0]),  ss0 = ih2(L[1]),  ns0 = ih2(L[2]);
    h2 cc1 = ih2(L[3]),  ss1 = ih2(L[4]),  ns1 = ih2(L[5]);
    h2 cc2 = ih2(L[6]),  ss2 = ih2(L[7]),  ns2 = ih2(L[8]);
    h2 cc3 = ih2(L[9]),  ss3 = ih2(L[10]), ns3 = ih2(L[11]);
    h2 cc4 = ih2(L[12]), ss4 = ih2(L[13]), ns4 = ih2(L[14]);
    h2 cc5 = ih2(L[15]), ss5 = ih2(L[16]), ns5 = ih2(L[17]);

    // composed lane-lane CNOTs: one bpermute per packed reg
#pragma unroll
    for (int i = 0; i < 8; ++i) x[i] = bper(addrP, x[i]);
    // CNOT(6,7): A2=1: swap A1 -> 4<->6, 5<->7
    { h2 t = x[4]; x[4] = x[6]; x[6] = t; t = x[5]; x[5] = x[7]; x[7] = t; }
    // CNOT(8,9): comp-swap on A0=1 -> deferred; CNOT(7,8): A1=1: swap A0 -> 2<->3, 6<->7
    { h2 t = x[2]; x[2] = x[3]; x[3] = t; t = x[6]; x[6] = x[7]; x[7] = t; }
    // deferred comp-swap flags now on regs {1,2,5,6}

    // RY wire9 (packed halves), absorbing deferred swap via operand order
#pragma unroll
    for (int i = 0; i < 8; ++i) {
      h2 t = hswap(x[i]);
      bool flg = (i == 1 || i == 2 || i == 5 || i == 6);
      x[i] = flg ? (h2)(t * cc9 + x[i] * ms9) : (h2)(x[i] * cc9 + t * ms9);
    }

    // RY wire6 (A2), absorbing CNOT(5,6): lane-conditioned coefficient variants
    {
      h2 AA = cb1 ? ns6 : cc6;
      h2 BB = cb1 ? cc6 : ns6;
      h2 CC = cb1 ? cc6 : ss6;
      h2 DD = cb1 ? ss6 : cc6;
#pragma unroll
      for (int i = 0; i < 4; ++i) {
        h2 u = x[i], w = x[i + 4];
        x[i]     = u * AA + w * BB;
        x[i + 4] = u * CC + w * DD;
      }
    }
    // RY wire7 (A1)
#pragma unroll
    for (int i = 0; i < 8; ++i) if (!(i & 2)) {
      h2 u = x[i], w = x[i | 2];
      x[i]     = u * cc7 + w * ns7;
      x[i | 2] = w * cc7 + u * ss7;
    }
    // RY wire8 (A0)
#pragma unroll
    for (int i = 0; i < 8; ++i) if (!(i & 1)) {
      h2 u = x[i], w = x[i | 1];
      x[i]     = u * cc8 + w * ns8;
      x[i | 1] = w * cc8 + u * ss8;
    }

    // RY wire0 (lane bit5): permlane32 pair-trick
#pragma unroll
    for (int j = 0; j < 4; ++j) {
      int a = h2i(x[2 * j]), b = h2i(x[2 * j + 1]);
      pl32s(a, b);
      h2 u = ih2(a), v = ih2(b);
      h2 nu = u * cc0 + v * ns0;
      h2 nv = v * cc0 + u * ss0;
      int na = h2i(nu), nb = h2i(nv);
      pl32s(na, nb);
      x[2 * j] = ih2(na); x[2 * j + 1] = ih2(nb);
    }
    // RY wire1 (lane bit4): permlane16 pair-trick
#pragma unroll
    for (int j = 0; j < 4; ++j) {
      int a = h2i(x[2 * j]), b = h2i(x[2 * j + 1]);
      pl16s(a, b);
      h2 u = ih2(a), v = ih2(b);
      h2 nu = u * cc1 + v * ns1;
      h2 nv = v * cc1 + u * ss1;
      int na = h2i(nu), nb = h2i(nv);
      pl16s(na, nb);
      x[2 * j] = ih2(na); x[2 * j + 1] = ih2(nb);
    }
    // RY wire2 (lane bit3): bpermute xor8
    {
      h2 gg = (lane & 8) ? ss2 : ns2;
#pragma unroll
      for (int i = 0; i < 8; ++i) {
        h2 p = bper(addrX8, x[i]);
        x[i] = x[i] * cc2 + p * gg;
      }
    }
    // RY wire3 (lane bit2): bpermute xor4
    {
      h2 gg = (lane & 4) ? ss3 : ns3;
#pragma unroll
      for (int i = 0; i < 8; ++i) {
        h2 p = bper(addrX4, x[i]);
        x[i] = x[i] * cc3 + p * gg;
      }
    }
    // RY wire4 (lane bit1): DPP quad_perm xor2
    {
      h2 gg = (lane & 2) ? ss4 : ns4;
#pragma unroll
      for (int i = 0; i < 8; ++i) {
        h2 p = dpph<0x4E>(x[i]);
        x[i] = x[i] * cc4 + p * gg;
      }
    }
    // RY wire5 (lane bit0): DPP quad_perm xor1
    {
      h2 gg = (lane & 1) ? ss5 : ns5;
#pragma unroll
      for (int i = 0; i < 8; ++i) {
        h2 p = dpph<0xB1>(x[i]);
        x[i] = x[i] * cc5 + p * gg;
      }
    }
  }

  // ---- expval Z (f32 squares; binned sums) ----
  float q[8], d9 = 0.f;
#pragma unroll
  for (int i = 0; i < 8; ++i) {
    float lo = (float)x[i].x, hi = (float)x[i].y;
    float a2 = lo * lo, b2 = hi * hi;
    q[i] = a2 + b2;
    d9 += a2 - b2;
  }
  float A = q[0] + q[1], Bq = q[2] + q[3], C = q[4] + q[5], D = q[6] + q[7];
  float S  = (A + Bq) + (C + D);
  float z6 = (A + Bq) - (C + D);
  float z7 = (A - Bq) + (C - D);
  float E = q[0] - q[1], F = q[2] - q[3], G = q[4] - q[5], H = q[6] - q[7];
  float z8 = (E + F) + (G + H);
  float z9 = d9;

  // wires 0..5: z_w = ±S by lane bit; project onto W_post before reducing
  float A0 = 0.f, A1 = 0.f;
#pragma unroll
  for (int w = 0; w < 6; ++w) {
    bool b = (lane >> (5 - w)) & 1;
    A0 += b ? -Wpost[w] : Wpost[w];
    A1 += b ? -Wpost[10 + w] : Wpost[10 + w];
  }
  float o0 = A0 * S + Wpost[6] * z6 + Wpost[7] * z7 + Wpost[8] * z8 + Wpost[9] * z9;
  float o1 = A1 * S + Wpost[16] * z6 + Wpost[17] * z7 + Wpost[18] * z8 + Wpost[19] * z9;
  o0 = wave_sum(o0);
  o1 = wave_sum(o1);
  if (lane == 63) {
    out[2 * (size_t)wv]     = o0 + bpost[0];
    out[2 * (size_t)wv + 1] = o1 + bpost[1];
  }
}

extern "C" void kernel_launch(void* const* d_in, const int* in_sizes, int n_in,
                              void* d_out, int out_size, void* d_ws, size_t ws_size,
                              hipStream_t stream) {
  const float* inp   = (const float*)d_in[0];
  const float* Wred  = (const float*)d_in[1];
  const float* bred  = (const float*)d_in[2];
  const float* qp    = (const float*)d_in[3];
  const float* Wpost = (const float*)d_in[4];
  const float* bpost = (const float*)d_in[5];
  float* out = (float*)d_out;
  unsigned* cbuf = (unsigned*)d_ws;

  int B = in_sizes[0] / 512;
  setup_kernel<<<1, 64, 0, stream>>>(qp, cbuf);
  int threads = 256;
  int blocks = (B * 64 + threads - 1) / threads;
  qnet_kernel<<<blocks, threads, 0, stream>>>(inp, Wred, bred, cbuf, Wpost, bpost, out, B);
}

// Round 6
// 99.228 us; speedup vs baseline: 1.7057x; 1.0002x over previous
//
#include <hip/hip_runtime.h>
#include <math.h>

#define QDEPTH 6

typedef _Float16 h2 __attribute__((ext_vector_type(2)));

__device__ __forceinline__ int   h2i(h2 v)  { return __builtin_bit_cast(int, v); }
__device__ __forceinline__ h2    ih2(int v) { return __builtin_bit_cast(h2, v); }

__device__ __forceinline__ h2 cvt_pk(float a, float b) {
  return __builtin_bit_cast(h2, __builtin_amdgcn_cvt_pkrtz(a, b));
}

__device__ __forceinline__ h2 bper(int addr, h2 v) {
  return ih2(__builtin_amdgcn_ds_bpermute(addr, h2i(v)));
}

template<int CTRL>
__device__ __forceinline__ h2 dpph(h2 v) {
  int i = h2i(v);
  return ih2(__builtin_amdgcn_update_dpp(i, i, CTRL, 0xF, 0xF, true));
}

template<int CTRL>
__device__ __forceinline__ float dpp_add0(float v) {
  int i = __float_as_int(v);
  int r = __builtin_amdgcn_update_dpp(0, i, CTRL, 0xF, 0xF, false);
  return v + __int_as_float(r);
}

// full-wave sum; result valid in lane 63
__device__ __forceinline__ float wave_sum(float v) {
  v = dpp_add0<0x111>(v);
  v = dpp_add0<0x112>(v);
  v = dpp_add0<0x114>(v);
  v = dpp_add0<0x118>(v);
  v = dpp_add0<0x142>(v);
  v = dpp_add0<0x143>(v);
  return v;
}

__device__ __forceinline__ float bcast63(float v) {
  return __int_as_float(__builtin_amdgcn_readlane(__float_as_int(v), 63));
}

__device__ __forceinline__ void pl32s(int& a, int& b) {
  asm("v_permlane32_swap_b32 %0, %1" : "+v"(a), "+v"(b));
}
__device__ __forceinline__ void pl16s(int& a, int& b) {
  asm("v_permlane16_swap_b32 %0, %1" : "+v"(a), "+v"(b));
}

// ---------------- setup: batch-independent packed f16 gate coefficients ----
// layout: per layer k (stride 32 u32): wire w<9 at w*3: {cc, ss, ns}; wire9 at 27: {cc9, ms9=(-s,+s)}
__global__ void setup_kernel(const float* __restrict__ qp, unsigned* __restrict__ cb) {
  int t = threadIdx.x;
  if (t >= 60) return;
  int k = t / 10, w = t % 10;
  float ang = qp[(k + 1) * 10 + w] * 0.5f;
  float c = __cosf(ang), s = __sinf(ang);
  unsigned* p = cb + k * 32 + ((w < 9) ? w * 3 : 27);
  h2 cc = { (_Float16)c, (_Float16)c };
  if (w < 9) {
    h2 ss = { (_Float16)s,  (_Float16)s };
    h2 ns = { (_Float16)(-s), (_Float16)(-s) };
    p[0] = __builtin_bit_cast(unsigned, cc);
    p[1] = __builtin_bit_cast(unsigned, ss);
    p[2] = __builtin_bit_cast(unsigned, ns);
  } else {
    h2 ms = { (_Float16)(-s), (_Float16)s };
    p[0] = __builtin_bit_cast(unsigned, cc);
    p[1] = __builtin_bit_cast(unsigned, ms);
  }
}

// ---------------- main ----------------
// grid is exact: B*64 threads, 256/block. No early-return (block barrier below).
__global__ void __launch_bounds__(256) qnet_kernel(
    const float* __restrict__ inp,   // B x 512
    const float* __restrict__ Wred,  // 10 x 512
    const float* __restrict__ bred,  // 10
    const unsigned* __restrict__ cb, // packed coefficients (from setup)
    const float* __restrict__ Wpost, // 2 x 10
    const float* __restrict__ bpost, // 2
    float* __restrict__ out,         // B x 2
    int B) {
  // coefficients -> LDS (DS-pipe reads in the loop share lgkmcnt ordering
  // with ds_bpermute; no SMEM/DS mixed-counter full drains)
  __shared__ unsigned sco[QDEPTH * 29];
  int tt = threadIdx.x;
  if (tt < QDEPTH * 29) sco[tt] = cb[(tt / 29) * 32 + (tt % 29)];
  __syncthreads();

  int tid  = blockIdx.x * 256 + threadIdx.x;
  int wv   = tid >> 6;
  int lane = tid & 63;

  // composed lane permutation of the layer's 5 lane-lane CNOTs (even then odd)
  int o = lane ^ (((lane >> 4) & 1) << 3) ^ (((lane >> 2) & 1) << 1);
  int psrc = o ^ (((o >> 5) & 1) << 4) ^ (((o >> 3) & 1) << 2) ^ ((o >> 1) & 1);
  int addrP  = psrc << 2;
  int addrX4 = (lane ^ 4) << 2;
  bool cb1 = lane & 1;

  // ---- fused pre-GEMM (float4) ----
  const float4* row4 = (const float4*)(inp + (size_t)wv * 512);
  float4 a0 = row4[lane], a1 = row4[lane + 64];
  float th[10];
#pragma unroll
  for (int q = 0; q < 10; ++q) {
    const float4* w4 = (const float4*)(Wred + q * 512);
    float4 b0 = w4[lane], b1 = w4[lane + 64];
    float t = a0.x * b0.x + a0.y * b0.y + a0.z * b0.z + a0.w * b0.w;
    t += a1.x * b1.x + a1.y * b1.y + a1.z * b1.z + a1.w * b1.w;
    th[q] = t;
  }

  // ---- per-qubit product-state factors: H then RY(q_in) ----
  float g0[10], g1[10];
#pragma unroll
  for (int q = 0; q < 10; ++q) {
    float tot = bcast63(wave_sum(th[q])) + bred[q];
    float xc = fminf(fmaxf(tot, -15.f), 15.f);
    float u = __expf(2.f * xc);
    float tanhv = (u - 1.f) * __builtin_amdgcn_rcpf(u + 1.f);
    float t = tanhv * 0.78539816339744831f;  // theta/2 = tanh * pi/4
    float c = __cosf(t), s = __sinf(t);
    g0[q] = (c - s) * 0.70710678118654752f;
    g1[q] = (c + s) * 0.70710678118654752f;
  }
  float lf = 1.f;
#pragma unroll
  for (int w = 0; w < 6; ++w)
    lf *= ((lane >> (5 - w)) & 1) ? g1[w] : g0[w];
  float f67v[4];
#pragma unroll
  for (int j = 0; j < 4; ++j)
    f67v[j] = ((j & 2) ? g1[6] : g0[6]) * ((j & 1) ? g1[7] : g0[7]);
  float F89x[2], F89y[2];
  F89x[0] = g0[8] * g0[9]; F89y[0] = g0[8] * g1[9];
  F89x[1] = g1[8] * g0[9]; F89y[1] = g1[8] * g1[9];

  // state: 8 packed regs; reg i = (A2 A1 A0) = amp bits from wires 6,7,8;
  // packed halves = wire 9 (comp bit).
  h2 x[8];
#pragma unroll
  for (int i = 0; i < 8; ++i) {
    float m = lf * f67v[i >> 1];
    x[i] = cvt_pk(m * F89x[i & 1], m * F89y[i & 1]);
  }

  // ---- entangling layers ----
  for (int k = 0; k < QDEPTH; ++k) {
    const unsigned* L = sco + k * 29;   // LDS, uniform addr -> broadcast reads
    h2 cc9 = ih2(L[27]), ms9 = ih2(L[28]);
    h2 cc6 = ih2(L[18]), ss6 = ih2(L[19]), ns6 = ih2(L[20]);
    h2 cc7 = ih2(L[21]), ss7 = ih2(L[22]), ns7 = ih2(L[23]);
    h2 cc8 = ih2(L[24]), ss8 = ih2(L[25]), ns8 = ih2(L[26]);
    h2 cc0 = ih2(L[0]),  ss0 = ih2(L[1]),  ns0 = ih2(L[2]);
    h2 cc1 = ih2(L[3]),  ss1 = ih2(L[4]),  ns1 = ih2(L[5]);
    h2 cc2 = ih2(L[6]),  ss2 = ih2(L[7]),  ns2 = ih2(L[8]);
    h2 cc3 = ih2(L[9]),  ss3 = ih2(L[10]), ns3 = ih2(L[11]);
    h2 cc4 = ih2(L[12]), ss4 = ih2(L[13]), ns4 = ih2(L[14]);
    h2 cc5 = ih2(L[15]), ss5 = ih2(L[16]), ns5 = ih2(L[17]);

    // composed lane-lane CNOTs: one bpermute per packed reg
#pragma unroll
    for (int i = 0; i < 8; ++i) x[i] = bper(addrP, x[i]);
    // CNOT(6,7): A2=1: swap A1 -> 4<->6, 5<->7
    { h2 t = x[4]; x[4] = x[6]; x[6] = t; t = x[5]; x[5] = x[7]; x[7] = t; }
    // CNOT(8,9): comp-swap on A0=1 -> deferred; CNOT(7,8): A1=1: swap A0 -> 2<->3, 6<->7
    { h2 t = x[2]; x[2] = x[3]; x[3] = t; t = x[6]; x[6] = x[7]; x[7] = t; }
    // deferred comp-swap flags now on regs {1,2,5,6}

    // RY wire9 (packed halves), absorbing deferred swap via operand order;
    // half-swap folds into v_pk op_sel
#pragma unroll
    for (int i = 0; i < 8; ++i) {
      h2 t = __builtin_shufflevector(x[i], x[i], 1, 0);
      bool flg = (i == 1 || i == 2 || i == 5 || i == 6);
      x[i] = flg ? (h2)(t * cc9 + x[i] * ms9) : (h2)(x[i] * cc9 + t * ms9);
    }

    // RY wire6 (A2), absorbing CNOT(5,6): lane-conditioned coefficient variants
    {
      h2 AA = cb1 ? ns6 : cc6;
      h2 BB = cb1 ? cc6 : ns6;
      h2 CC = cb1 ? cc6 : ss6;
      h2 DD = cb1 ? ss6 : cc6;
#pragma unroll
      for (int i = 0; i < 4; ++i) {
        h2 u = x[i], w = x[i + 4];
        x[i]     = u * AA + w * BB;
        x[i + 4] = u * CC + w * DD;
      }
    }
    // RY wire7 (A1)
#pragma unroll
    for (int i = 0; i < 8; ++i) if (!(i & 2)) {
      h2 u = x[i], w = x[i | 2];
      x[i]     = u * cc7 + w * ns7;
      x[i | 2] = w * cc7 + u * ss7;
    }
    // RY wire8 (A0)
#pragma unroll
    for (int i = 0; i < 8; ++i) if (!(i & 1)) {
      h2 u = x[i], w = x[i | 1];
      x[i]     = u * cc8 + w * ns8;
      x[i | 1] = w * cc8 + u * ss8;
    }

    // RY wire0 (lane bit5): permlane32 pair-trick
#pragma unroll
    for (int j = 0; j < 4; ++j) {
      int a = h2i(x[2 * j]), b = h2i(x[2 * j + 1]);
      pl32s(a, b);
      h2 u = ih2(a), v = ih2(b);
      h2 nu = u * cc0 + v * ns0;
      h2 nv = v * cc0 + u * ss0;
      int na = h2i(nu), nb = h2i(nv);
      pl32s(na, nb);
      x[2 * j] = ih2(na); x[2 * j + 1] = ih2(nb);
    }
    // RY wire1 (lane bit4): permlane16 pair-trick
#pragma unroll
    for (int j = 0; j < 4; ++j) {
      int a = h2i(x[2 * j]), b = h2i(x[2 * j + 1]);
      pl16s(a, b);
      h2 u = ih2(a), v = ih2(b);
      h2 nu = u * cc1 + v * ns1;
      h2 nv = v * cc1 + u * ss1;
      int na = h2i(nu), nb = h2i(nv);
      pl16s(na, nb);
      x[2 * j] = ih2(na); x[2 * j + 1] = ih2(nb);
    }
    // RY wire2 (lane bit3): DPP row_ror:8 (xor8 within 16-lane row)
    {
      h2 gg = (lane & 8) ? ss2 : ns2;
#pragma unroll
      for (int i = 0; i < 8; ++i) {
        h2 p = dpph<0x128>(x[i]);
        x[i] = x[i] * cc2 + p * gg;
      }
    }
    // RY wire3 (lane bit2): bpermute xor4
    {
      h2 gg = (lane & 4) ? ss3 : ns3;
#pragma unroll
      for (int i = 0; i < 8; ++i) {
        h2 p = bper(addrX4, x[i]);
        x[i] = x[i] * cc3 + p * gg;
      }
    }
    // RY wire4 (lane bit1): DPP quad_perm xor2
    {
      h2 gg = (lane & 2) ? ss4 : ns4;
#pragma unroll
      for (int i = 0; i < 8; ++i) {
        h2 p = dpph<0x4E>(x[i]);
        x[i] = x[i] * cc4 + p * gg;
      }
    }
    // RY wire5 (lane bit0): DPP quad_perm xor1
    {
      h2 gg = (lane & 1) ? ss5 : ns5;
#pragma unroll
      for (int i = 0; i < 8; ++i) {
        h2 p = dpph<0xB1>(x[i]);
        x[i] = x[i] * cc5 + p * gg;
      }
    }
  }

  // ---- expval Z (f32 squares; binned sums) ----
  float q[8], d9 = 0.f;
#pragma unroll
  for (int i = 0; i < 8; ++i) {
    float lo = (float)x[i].x, hi = (float)x[i].y;
    float a2 = lo * lo, b2 = hi * hi;
    q[i] = a2 + b2;
    d9 += a2 - b2;
  }
  float A = q[0] + q[1], Bq = q[2] + q[3], C = q[4] + q[5], D = q[6] + q[7];
  float S  = (A + Bq) + (C + D);
  float z6 = (A + Bq) - (C + D);
  float z7 = (A - Bq) + (C - D);
  float E = q[0] - q[1], F = q[2] - q[3], G = q[4] - q[5], H = q[6] - q[7];
  float z8 = (E + F) + (G + H);
  float z9 = d9;

  // wires 0..5: z_w = ±S by lane bit; project onto W_post before reducing
  float A0 = 0.f, A1 = 0.f;
#pragma unroll
  for (int w = 0; w < 6; ++w) {
    bool b = (lane >> (5 - w)) & 1;
    A0 += b ? -Wpost[w] : Wpost[w];
    A1 += b ? -Wpost[10 + w] : Wpost[10 + w];
  }
  float o0 = A0 * S + Wpost[6] * z6 + Wpost[7] * z7 + Wpost[8] * z8 + Wpost[9] * z9;
  float o1 = A1 * S + Wpost[16] * z6 + Wpost[17] * z7 + Wpost[18] * z8 + Wpost[19] * z9;
  o0 = wave_sum(o0);
  o1 = wave_sum(o1);
  if (lane == 63) {
    float2 ov = { o0 + bpost[0], o1 + bpost[1] };
    *(float2*)(out + 2 * (size_t)wv) = ov;
  }
}

extern "C" void kernel_launch(void* const* d_in, const int* in_sizes, int n_in,
                              void* d_out, int out_size, void* d_ws, size_t ws_size,
                              hipStream_t stream) {
  const float* inp   = (const float*)d_in[0];
  const float* Wred  = (const float*)d_in[1];
  const float* bred  = (const float*)d_in[2];
  const float* qp    = (const float*)d_in[3];
  const float* Wpost = (const float*)d_in[4];
  const float* bpost = (const float*)d_in[5];
  float* out = (float*)d_out;
  unsigned* cbuf = (unsigned*)d_ws;

  int B = in_sizes[0] / 512;
  setup_kernel<<<1, 64, 0, stream>>>(qp, cbuf);
  int blocks = (B * 64) / 256;   // exact: B is a multiple of 4
  qnet_kernel<<<blocks, 256, 0, stream>>>(inp, Wred, bred, cbuf, Wpost, bpost, out, B);
}

// Round 7
// 99.021 us; speedup vs baseline: 1.7093x; 1.0021x over previous
//
#include <hip/hip_runtime.h>
#include <math.h>

#define QDEPTH 6

typedef _Float16 h2 __attribute__((ext_vector_type(2)));

__device__ __forceinline__ int   h2i(h2 v)  { return __builtin_bit_cast(int, v); }
__device__ __forceinline__ h2    ih2(int v) { return __builtin_bit_cast(h2, v); }
__device__ __forceinline__ unsigned h2u(h2 v) { return __builtin_bit_cast(unsigned, v); }

__device__ __forceinline__ h2 cvt_pk(float a, float b) {
  return __builtin_bit_cast(h2, __builtin_amdgcn_cvt_pkrtz(a, b));
}

__device__ __forceinline__ h2 bper(int addr, h2 v) {
  return ih2(__builtin_amdgcn_ds_bpermute(addr, h2i(v)));
}

template<int CTRL>
__device__ __forceinline__ h2 dpph(h2 v) {
  int i = h2i(v);
  return ih2(__builtin_amdgcn_update_dpp(i, i, CTRL, 0xF, 0xF, true));
}

template<int CTRL>
__device__ __forceinline__ float dpp_add0(float v) {
  int i = __float_as_int(v);
  int r = __builtin_amdgcn_update_dpp(0, i, CTRL, 0xF, 0xF, false);
  return v + __int_as_float(r);
}

// full-wave sum; result valid in lane 63
__device__ __forceinline__ float wave_sum(float v) {
  v = dpp_add0<0x111>(v);
  v = dpp_add0<0x112>(v);
  v = dpp_add0<0x114>(v);
  v = dpp_add0<0x118>(v);
  v = dpp_add0<0x142>(v);
  v = dpp_add0<0x143>(v);
  return v;
}

__device__ __forceinline__ float bcast63(float v) {
  return __int_as_float(__builtin_amdgcn_readlane(__float_as_int(v), 63));
}

__device__ __forceinline__ void pl32s(int& a, int& b) {
  asm("v_permlane32_swap_b32 %0, %1" : "+v"(a), "+v"(b));
}
__device__ __forceinline__ void pl16s(int& a, int& b) {
  asm("v_permlane16_swap_b32 %0, %1" : "+v"(a), "+v"(b));
}

// ---------------- main ----------------
// One wave handles TWO batch elements: x[0..7] = element A, x[8..15] = element B.
// Per element: reg index (A2 A1 A0) = wires 6,7,8; packed f16 halves = wire 9;
// lane bits 5..0 = wires 0..5.
__global__ void __launch_bounds__(256) qnet_kernel(
    const float* __restrict__ inp,   // B x 512
    const float* __restrict__ Wred,  // 10 x 512
    const float* __restrict__ bred,  // 10
    const float* __restrict__ qp,    // 15 x 10
    const float* __restrict__ Wpost, // 2 x 10
    const float* __restrict__ bpost, // 2
    float* __restrict__ out,         // B x 2
    int B) {
  // ---- per-block coefficient table (fused former setup kernel) ----
  // layer k stride 29: wire w<9 at w*3: {cc, ss, ns}; wire9 at 27: {cc9, ms9=(-s,+s)}
  __shared__ unsigned sco[QDEPTH * 29];
  {
    int t = threadIdx.x;
    if (t < 60) {
      int k = t / 10, w = t % 10;
      float ang = qp[(k + 1) * 10 + w] * 0.5f;
      float c = __cosf(ang), s = __sinf(ang);
      _Float16 ch = (_Float16)c, sh = (_Float16)s, nh = (_Float16)(-s);
      if (w < 9) {
        sco[k * 29 + w * 3 + 0] = h2u((h2){ch, ch});
        sco[k * 29 + w * 3 + 1] = h2u((h2){sh, sh});
        sco[k * 29 + w * 3 + 2] = h2u((h2){nh, nh});
      } else {
        sco[k * 29 + 27] = h2u((h2){ch, ch});
        sco[k * 29 + 28] = h2u((h2){nh, sh});
      }
    }
  }
  __syncthreads();

  int tid  = blockIdx.x * 256 + threadIdx.x;
  int wv   = tid >> 6;     // wave id; elements 2wv, 2wv+1
  int lane = tid & 63;

  // composed lane permutation of the layer's 5 lane-lane CNOTs (even then odd)
  int o = lane ^ (((lane >> 4) & 1) << 3) ^ (((lane >> 2) & 1) << 1);
  int psrc = o ^ (((o >> 5) & 1) << 4) ^ (((o >> 3) & 1) << 2) ^ ((o >> 1) & 1);
  int addrP  = psrc << 2;
  int addrX4 = (lane ^ 4) << 2;
  bool cb1 = lane & 1;

  // ---- fused pre-GEMM (float4), two rows, shared Wred loads ----
  const float4* rA = (const float4*)(inp + (size_t)(2 * wv) * 512);
  const float4* rB = (const float4*)(inp + (size_t)(2 * wv + 1) * 512);
  float4 A0 = rA[lane], A1 = rA[lane + 64];
  float4 B0 = rB[lane], B1 = rB[lane + 64];
  float thA[10], thB[10];
#pragma unroll
  for (int q = 0; q < 10; ++q) {
    const float4* w4 = (const float4*)(Wred + q * 512);
    float4 w0 = w4[lane], w1 = w4[lane + 64];
    thA[q] = A0.x * w0.x + A0.y * w0.y + A0.z * w0.z + A0.w * w0.w
           + A1.x * w1.x + A1.y * w1.y + A1.z * w1.z + A1.w * w1.w;
    thB[q] = B0.x * w0.x + B0.y * w0.y + B0.z * w0.z + B0.w * w0.w
           + B1.x * w1.x + B1.y * w1.y + B1.z * w1.z + B1.w * w1.w;
  }

  h2 x[16];

  // ---- product-state init per element (H + RY(q_in) layers fused) ----
#pragma unroll
  for (int e = 0; e < 2; ++e) {
    float g0[10], g1[10];
#pragma unroll
    for (int q = 0; q < 10; ++q) {
      float tot = bcast63(wave_sum(e ? thB[q] : thA[q])) + bred[q];
      float xc = fminf(fmaxf(tot, -15.f), 15.f);
      float u = __expf(2.f * xc);
      float tanhv = (u - 1.f) * __builtin_amdgcn_rcpf(u + 1.f);
      float t = tanhv * 0.78539816339744831f;  // theta/2 = tanh * pi/4
      float c = __cosf(t), s = __sinf(t);
      g0[q] = (c - s) * 0.70710678118654752f;
      g1[q] = (c + s) * 0.70710678118654752f;
    }
    float lf = 1.f;
#pragma unroll
    for (int w = 0; w < 6; ++w)
      lf *= ((lane >> (5 - w)) & 1) ? g1[w] : g0[w];
    float f67v[4];
#pragma unroll
    for (int j = 0; j < 4; ++j)
      f67v[j] = ((j & 2) ? g1[6] : g0[6]) * ((j & 1) ? g1[7] : g0[7]);
    float F89x[2], F89y[2];
    F89x[0] = g0[8] * g0[9]; F89y[0] = g0[8] * g1[9];
    F89x[1] = g1[8] * g0[9]; F89y[1] = g1[8] * g1[9];
#pragma unroll
    for (int i = 0; i < 8; ++i) {
      float m = lf * f67v[i >> 1];
      x[e * 8 + i] = cvt_pk(m * F89x[i & 1], m * F89y[i & 1]);
    }
  }

  // ---- entangling layers (both elements interleaved for 16-wide ILP) ----
#pragma unroll
  for (int k = 0; k < QDEPTH; ++k) {
    const unsigned* L = sco + k * 29;   // LDS, uniform addr -> broadcast reads

    // composed lane-lane CNOTs: one bpermute per packed reg
#pragma unroll
    for (int i = 0; i < 16; ++i) x[i] = bper(addrP, x[i]);
    // CNOT(6,7): A2=1: swap A1 -> (4,6),(5,7) per half
#pragma unroll
    for (int e = 0; e < 16; e += 8) {
      h2 t = x[e + 4]; x[e + 4] = x[e + 6]; x[e + 6] = t;
      t = x[e + 5]; x[e + 5] = x[e + 7]; x[e + 7] = t;
    }
    // CNOT(8,9) deferred into RY9; CNOT(7,8): A1=1: swap A0 -> (2,3),(6,7) per half
#pragma unroll
    for (int e = 0; e < 16; e += 8) {
      h2 t = x[e + 2]; x[e + 2] = x[e + 3]; x[e + 3] = t;
      t = x[e + 6]; x[e + 6] = x[e + 7]; x[e + 7] = t;
    }
    // deferred comp-swap flags now on (i&7) in {1,2,5,6}

    // RY wire9 (packed halves), absorbing deferred swap via operand order
    { h2 cc9 = ih2(L[27]), ms9 = ih2(L[28]);
#pragma unroll
      for (int i = 0; i < 16; ++i) {
        h2 t = __builtin_shufflevector(x[i], x[i], 1, 0);
        int m = i & 7;
        bool flg = (m == 1 || m == 2 || m == 5 || m == 6);
        x[i] = flg ? (h2)(t * cc9 + x[i] * ms9) : (h2)(x[i] * cc9 + t * ms9);
      } }

    // RY wire6 (A2), absorbing CNOT(5,6): lane-conditioned coefficient variants
    { h2 cc6 = ih2(L[18]), ss6 = ih2(L[19]), ns6 = ih2(L[20]);
      h2 AA = cb1 ? ns6 : cc6;
      h2 BB = cb1 ? cc6 : ns6;
      h2 CC = cb1 ? cc6 : ss6;
      h2 DD = cb1 ? ss6 : cc6;
#pragma unroll
      for (int i = 0; i < 16; ++i) if (!(i & 4)) {
        h2 u = x[i], w = x[i + 4];
        x[i]     = u * AA + w * BB;
        x[i + 4] = u * CC + w * DD;
      } }
    // RY wire7 (A1)
    { h2 cc7 = ih2(L[21]), ss7 = ih2(L[22]), ns7 = ih2(L[23]);
#pragma unroll
      for (int i = 0; i < 16; ++i) if (!(i & 2)) {
        h2 u = x[i], w = x[i | 2];
        x[i]     = u * cc7 + w * ns7;
        x[i | 2] = w * cc7 + u * ss7;
      } }
    // RY wire8 (A0)
    { h2 cc8 = ih2(L[24]), ss8 = ih2(L[25]), ns8 = ih2(L[26]);
#pragma unroll
      for (int i = 0; i < 16; ++i) if (!(i & 1)) {
        h2 u = x[i], w = x[i | 1];
        x[i]     = u * cc8 + w * ns8;
        x[i | 1] = w * cc8 + u * ss8;
      } }

    // RY wire0 (lane bit5): permlane32 pair-trick
    { h2 cc0 = ih2(L[0]), ss0 = ih2(L[1]), ns0 = ih2(L[2]);
#pragma unroll
      for (int j = 0; j < 8; ++j) {
        int a = h2i(x[2 * j]), b = h2i(x[2 * j + 1]);
        pl32s(a, b);
        h2 u = ih2(a), v = ih2(b);
        h2 nu = u * cc0 + v * ns0;
        h2 nv = v * cc0 + u * ss0;
        int na = h2i(nu), nb = h2i(nv);
        pl32s(na, nb);
        x[2 * j] = ih2(na); x[2 * j + 1] = ih2(nb);
      } }
    // RY wire1 (lane bit4): permlane16 pair-trick
    { h2 cc1 = ih2(L[3]), ss1 = ih2(L[4]), ns1 = ih2(L[5]);
#pragma unroll
      for (int j = 0; j < 8; ++j) {
        int a = h2i(x[2 * j]), b = h2i(x[2 * j + 1]);
        pl16s(a, b);
        h2 u = ih2(a), v = ih2(b);
        h2 nu = u * cc1 + v * ns1;
        h2 nv = v * cc1 + u * ss1;
        int na = h2i(nu), nb = h2i(nv);
        pl16s(na, nb);
        x[2 * j] = ih2(na); x[2 * j + 1] = ih2(nb);
      } }
    // RY wire2 (lane bit3): DPP row_ror:8 (xor8 within 16-lane row)
    { h2 cc2 = ih2(L[6]), ss2 = ih2(L[7]), ns2 = ih2(L[8]);
      h2 gg = (lane & 8) ? ss2 : ns2;
#pragma unroll
      for (int i = 0; i < 16; ++i) {
        h2 p = dpph<0x128>(x[i]);
        x[i] = x[i] * cc2 + p * gg;
      } }
    // RY wire3 (lane bit2): bpermute xor4
    { h2 cc3 = ih2(L[9]), ss3 = ih2(L[10]), ns3 = ih2(L[11]);
      h2 gg = (lane & 4) ? ss3 : ns3;
#pragma unroll
      for (int i = 0; i < 16; ++i) {
        h2 p = bper(addrX4, x[i]);
        x[i] = x[i] * cc3 + p * gg;
      } }
    // RY wire4 (lane bit1): DPP quad_perm xor2
    { h2 cc4 = ih2(L[12]), ss4 = ih2(L[13]), ns4 = ih2(L[14]);
      h2 gg = (lane & 2) ? ss4 : ns4;
#pragma unroll
      for (int i = 0; i < 16; ++i) {
        h2 p = dpph<0x4E>(x[i]);
        x[i] = x[i] * cc4 + p * gg;
      } }
    // RY wire5 (lane bit0): DPP quad_perm xor1
    { h2 cc5 = ih2(L[15]), ss5 = ih2(L[16]), ns5 = ih2(L[17]);
      h2 gg = (lane & 1) ? ss5 : ns5;
#pragma unroll
      for (int i = 0; i < 16; ++i) {
        h2 p = dpph<0xB1>(x[i]);
        x[i] = x[i] * cc5 + p * gg;
      } }
  }

  // ---- expval Z + post-projection per element ----
  float A0w = 0.f, A1w = 0.f;
#pragma unroll
  for (int w = 0; w < 6; ++w) {
    bool b = (lane >> (5 - w)) & 1;
    A0w += b ? -Wpost[w] : Wpost[w];
    A1w += b ? -Wpost[10 + w] : Wpost[10 + w];
  }
  float oo[4];
#pragma unroll
  for (int e = 0; e < 2; ++e) {
    float q[8], d9 = 0.f;
#pragma unroll
    for (int i = 0; i < 8; ++i) {
      float lo = (float)x[e * 8 + i].x, hi = (float)x[e * 8 + i].y;
      float a2 = lo * lo, b2 = hi * hi;
      q[i] = a2 + b2;
      d9 += a2 - b2;
    }
    float A = q[0] + q[1], Bq = q[2] + q[3], C = q[4] + q[5], D = q[6] + q[7];
    float S  = (A + Bq) + (C + D);
    float z6 = (A + Bq) - (C + D);
    float z7 = (A - Bq) + (C - D);
    float E = q[0] - q[1], F = q[2] - q[3], G = q[4] - q[5], H = q[6] - q[7];
    float z8 = (E + F) + (G + H);
    float o0 = A0w * S + Wpost[6] * z6 + Wpost[7] * z7 + Wpost[8] * z8 + Wpost[9] * d9;
    float o1 = A1w * S + Wpost[16] * z6 + Wpost[17] * z7 + Wpost[18] * z8 + Wpost[19] * d9;
    oo[2 * e]     = wave_sum(o0);
    oo[2 * e + 1] = wave_sum(o1);
  }
  if (lane == 63) {
    float4 ov = { oo[0] + bpost[0], oo[1] + bpost[1],
                  oo[2] + bpost[0], oo[3] + bpost[1] };
    *(float4*)(out + 4 * (size_t)wv) = ov;
  }
}

extern "C" void kernel_launch(void* const* d_in, const int* in_sizes, int n_in,
                              void* d_out, int out_size, void* d_ws, size_t ws_size,
                              hipStream_t stream) {
  const float* inp   = (const float*)d_in[0];
  const float* Wred  = (const float*)d_in[1];
  const float* bred  = (const float*)d_in[2];
  const float* qp    = (const float*)d_in[3];
  const float* Wpost = (const float*)d_in[4];
  const float* bpost = (const float*)d_in[5];
  float* out = (float*)d_out;

  int B = in_sizes[0] / 512;
  int blocks = (B * 32) / 256;   // 2 elements per wave; exact for B % 8 == 0
  qnet_kernel<<<blocks, 256, 0, stream>>>(inp, Wred, bred, qp, Wpost, bpost, out, B);
}